// Round 4
// baseline (180.558 us; speedup 1.0000x reference)
//
#include <hip/hip_runtime.h>
#include <stdint.h>
#include <stddef.h>

// CliffordLinear as one bf16 GEMM:
//   out[b, o*8+l] = sum_{i,k} X[b, i*8+k] * Wt[o*8+l, i*8+k] + bias[o*8+l]
//   Wt[(o,l),(i,k)] = sum_j cayley[j,k,l] * W[o,i,j]
// M=8192, N=2048, K=2048. bf16 MFMA, fp32 accumulate.
//
// R11: restore cross-block pipe overlap. R9/R10 measured slice time = MFMA
// floor + LDS floor (serial sum): one 8-wave block in barrier lockstep keeps
// the CU's LDS pipe and matrix pipe in alternating eras, and instruction-
// level interleave (R10's SGB) only made it worse. Fix per m114: two
// INDEPENDENT blocks per CU drift into anti-phase, overlapping one block's
// MFMA era with the other's LDS era; setprio(1) around MFMA then has real
// role diversity to arbitrate (T5 prerequisite).
//   block = 256x128 tile, 256 threads (4 waves 2Mx2N, per-wave 128x64 --
//   same fragment pattern as R9), ring of 3 slots (A 16KB + B 8KB = 24KB
//   per slot, 72 KB LDS) -> 2 blocks/CU.
// Ring-3 schedule per slice s (two windows):
//   h0: read af1 (A m4-7, slot s%3) | stage A(s+2) | MFMA m0-3 | vmcnt(4) | bar
//   h1: read next-slice af0/bf (slot (s+1)%3) | stage B(s+2) | MFMA m4-7 | bar
// WAR: slot's last read completes before that window's MFMA lgkmcnt, >=1
// window + barrier before overwrite. RAW: vmcnt(4) leaves only A(s+2) in
// flight -> A(s+1),B(s+1) landed before h1 reads them; vmcnt(0) only at s=62.
// No SGB (R10 regression). Kept: quad-XOR source swizzle (0 conflicts),
// register ping-pong, vmcnt never 0 in steady loop, XCD swizzle, fused prep.

typedef __bf16 bf16x8  __attribute__((ext_vector_type(8)));
typedef float  f32x4   __attribute__((ext_vector_type(4)));

#define BM 256
#define BN 128
#define KSLICE 32
#define NSLICES 64               // K=2048 / 32
#define A_SLOT (256 * 32)        // 8192 elems = 16 KB
#define B_SLOT (128 * 32)        // 4096 elems = 8 KB

__device__ __forceinline__ void async_copy16(void* lds_dst, const void* g_src) {
    __builtin_amdgcn_global_load_lds(
        (__attribute__((address_space(1))) void*)g_src,
        (__attribute__((address_space(3))) void*)lds_dst,
        16, 0, 0);
}

// ---------------- kernel 1: fused prep (cast X -> bf16, fold Cayley) -------
__global__ __launch_bounds__(256) void prep_kernel(
    const float* __restrict__ x, __bf16* __restrict__ Xb, long nx,
    const float* __restrict__ W, const float* __restrict__ cayley,
    __bf16* __restrict__ Wt, int Cin, int Cout, int castBlocks)
{
    __shared__ float Cay[512];
    if ((int)blockIdx.x < castBlocks) {
        long i = ((long)blockIdx.x * 256 + threadIdx.x) * 8;
        if (i + 8 <= nx) {
            const f32x4* p = (const f32x4*)(x + i);
            f32x4 v0 = p[0];
            f32x4 v1 = p[1];
            bf16x8 o;
            o[0] = (__bf16)v0[0]; o[1] = (__bf16)v0[1];
            o[2] = (__bf16)v0[2]; o[3] = (__bf16)v0[3];
            o[4] = (__bf16)v1[0]; o[5] = (__bf16)v1[1];
            o[6] = (__bf16)v1[2]; o[7] = (__bf16)v1[3];
            *(bf16x8*)(Xb + i) = o;
        }
        return;
    }
    for (int t = threadIdx.x; t < 512; t += 256) Cay[t] = cayley[t];
    __syncthreads();

    int flat = (blockIdx.x - castBlocks) * 256 + threadIdx.x;  // n*Cin + i
    int total = Cout * 8 * Cin;
    if (flat >= total) return;
    int i = flat % Cin;
    int n = flat / Cin;
    int o = n >> 3, l = n & 7;

    const float* wrow = W + ((size_t)o * Cin + i) * 8;
    float w8[8];
    #pragma unroll
    for (int j = 0; j < 8; ++j) w8[j] = wrow[j];

    bf16x8 outv;
    #pragma unroll
    for (int k = 0; k < 8; ++k) {
        float s = 0.f;
        #pragma unroll
        for (int j = 0; j < 8; ++j) s += Cay[j * 64 + k * 8 + l] * w8[j];
        outv[k] = (__bf16)s;
    }
    *(bf16x8*)(Wt + (size_t)n * (Cin * 8) + i * 8) = outv;
}

// ---------------- kernel 2: bf16 GEMM, C = A * Bt^T + bias ----------------
__global__ __launch_bounds__(256, 2) void gemm_bt_kernel(
    const __bf16* __restrict__ A,
    const __bf16* __restrict__ Bt,
    const float*  __restrict__ bias,
    float* __restrict__ C,
    int M, int N, int K)
{
    __shared__ __align__(16) __bf16 As[3][A_SLOT];  // 3 x 16 KB
    __shared__ __align__(16) __bf16 Bs[3][B_SLOT];  // 3 x  8 KB

    const int tid  = threadIdx.x;
    const int wave = tid >> 6;    // 0..3
    const int lane = tid & 63;
    const int quad = lane >> 4;   // 0..3
    const int l16  = lane & 15;   // 0..15

    // --- XCD swizzle: 512 blocks, 8 XCDs; XCD x owns M-tiles [4x,4x+4) x all
    // 16 N-tiles. Bijective since 512 % 8 == 0.
    const int bid = blockIdx.x;
    const int xcd = bid & 7;
    const int idx = bid >> 3;                 // 0..63
    const int mBase = (xcd * 4 + (idx & 3)) * BM;
    const int nBase = (idx >> 2) * BN;

    // --- staging (quad-XOR source swizzle; LDS dest stays linear).
    // A: 16 KB/slice = 4 waves x 4 chunks x 1 KB (wave w rows 64w..64w+63).
    // B:  8 KB/slice = 4 waves x 2 chunks x 1 KB (wave w rows 32w..32w+31).
    const int srow = lane >> 2;                       // 0..15 row in chunk
    const int sgrp = (lane & 3) ^ ((lane >> 3) & 3);  // swizzled 16B group
    const __bf16* gA0 = A  + (size_t)(mBase + wave * 64 +  0 + srow) * K + sgrp * 8;
    const __bf16* gA1 = A  + (size_t)(mBase + wave * 64 + 16 + srow) * K + sgrp * 8;
    const __bf16* gA2 = A  + (size_t)(mBase + wave * 64 + 32 + srow) * K + sgrp * 8;
    const __bf16* gA3 = A  + (size_t)(mBase + wave * 64 + 48 + srow) * K + sgrp * 8;
    const __bf16* gB0 = Bt + (size_t)(nBase + wave * 32 +  0 + srow) * K + sgrp * 8;
    const __bf16* gB1 = Bt + (size_t)(nBase + wave * 32 + 16 + srow) * K + sgrp * 8;
    const int stA = wave * 2048;   // elements: (64*wave)*32
    const int stB = wave * 1024;   // elements: (32*wave)*32

#define STAGE_A(slot, q) do {                                               \
        async_copy16(&As[slot][stA       ], gA0 + (size_t)(q) * KSLICE);    \
        async_copy16(&As[slot][stA +  512], gA1 + (size_t)(q) * KSLICE);    \
        async_copy16(&As[slot][stA + 1024], gA2 + (size_t)(q) * KSLICE);    \
        async_copy16(&As[slot][stA + 1536], gA3 + (size_t)(q) * KSLICE);    \
    } while (0)
#define STAGE_B(slot, q) do {                                               \
        async_copy16(&Bs[slot][stB       ], gB0 + (size_t)(q) * KSLICE);    \
        async_copy16(&Bs[slot][stB +  512], gB1 + (size_t)(q) * KSLICE);    \
    } while (0)

    // --- compute: wave (wm,wn) owns a 128x64 sub-tile; 8x4 frags of 16x16.
    const int wm = wave >> 1;     // 0..1
    const int wn = wave & 1;      // 0..1
    const int offq = (quad ^ ((l16 >> 1) & 3)) * 8;
    const __bf16* paBase = &As[0][(wm * 128 + l16) * KSLICE + offq];
    const __bf16* pbBase = &Bs[0][(wn * 64  + l16) * KSLICE + offq];

    f32x4 acc[8][4] = {};
    bf16x8 af0A[4], bfA[4], af0B[4], bfB[4], af1[4];

    // --- prologue: stage A0,B0,A1,B1 (12 loads/thread). vmcnt(6) leaves
    // {A1,B1} in flight -> slice 0 landed. Barrier, pre-read slice-0 frags.
    STAGE_A(0, 0); STAGE_B(0, 0);
    STAGE_A(1, 1); STAGE_B(1, 1);
    asm volatile("s_waitcnt vmcnt(6)" ::: "memory");
    __builtin_amdgcn_s_barrier();

    #pragma unroll
    for (int j = 0; j < 4; ++j)
        af0A[j] = *(const bf16x8*)(paBase + j * 512);
    #pragma unroll
    for (int j = 0; j < 4; ++j)
        bfA[j]  = *(const bf16x8*)(pbBase + j * 512);

    // One slice = two windows.
    //  h0: read af1 (A m4-7, slot c_) | stage A(s+2) | MFMA m0-3 (AF0,BF)
    //      | vmcnt: A(s+1),B(s+1) landed (only A(s+2) in flight) | barrier
    //  h1: read slice s+1 frags (slot n_) into (NAF0,NBF) | stage B(s+2)
    //      | MFMA m4-7 (af1,BF) | barrier
#define SLICE_BODY(s_, c_, n_, AF0, BF, NAF0, NBF, DOA, DOB, DOPF, VM0)        \
    do {                                                                       \
        _Pragma("unroll")                                                      \
        for (int j = 0; j < 4; ++j)                                            \
            af1[j] = *(const bf16x8*)(paBase + (c_) * A_SLOT + (4 + j) * 512); \
        if (DOA) STAGE_A(((s_) + 2) % 3, (s_) + 2);                            \
        __builtin_amdgcn_s_setprio(1);                                         \
        _Pragma("unroll")                                                      \
        for (int j = 0; j < 4; ++j)                                            \
            _Pragma("unroll")                                                  \
            for (int n = 0; n < 4; ++n)                                        \
                acc[j][n] = __builtin_amdgcn_mfma_f32_16x16x32_bf16(           \
                    AF0[j], BF[n], acc[j][n], 0, 0, 0);                        \
        __builtin_amdgcn_s_setprio(0);                                         \
        if (VM0) asm volatile("s_waitcnt vmcnt(0)" ::: "memory");              \
        else     asm volatile("s_waitcnt vmcnt(4)" ::: "memory");              \
        __builtin_amdgcn_s_barrier();                                          \
        if (DOPF) {                                                            \
            _Pragma("unroll")                                                  \
            for (int j = 0; j < 4; ++j)                                        \
                NAF0[j] = *(const bf16x8*)(paBase + (n_) * A_SLOT + j * 512);  \
            _Pragma("unroll")                                                  \
            for (int j = 0; j < 4; ++j)                                        \
                NBF[j] = *(const bf16x8*)(pbBase + (n_) * B_SLOT + j * 512);   \
        }                                                                      \
        if (DOB) STAGE_B(((s_) + 2) % 3, (s_) + 2);                            \
        __builtin_amdgcn_s_setprio(1);                                         \
        _Pragma("unroll")                                                      \
        for (int j = 0; j < 4; ++j)                                            \
            _Pragma("unroll")                                                  \
            for (int n = 0; n < 4; ++n)                                        \
                acc[4 + j][n] = __builtin_amdgcn_mfma_f32_16x16x32_bf16(       \
                    af1[j], BF[n], acc[4 + j][n], 0, 0, 0);                    \
        __builtin_amdgcn_s_setprio(0);                                         \
        __builtin_amdgcn_s_barrier();                                          \
    } while (0)

    // --- main loop: 60 slices; 6-slice body aligns slot period (3) with
    // register ping-pong period (2). All guards compile-time.
    #pragma unroll 1
    for (int t = 0; t < 10; ++t) {
        SLICE_BODY(6 * t + 0, 0, 1, af0A, bfA, af0B, bfB, true, true, true, false);
        SLICE_BODY(6 * t + 1, 1, 2, af0B, bfB, af0A, bfA, true, true, true, false);
        SLICE_BODY(6 * t + 2, 2, 0, af0A, bfA, af0B, bfB, true, true, true, false);
        SLICE_BODY(6 * t + 3, 0, 1, af0B, bfB, af0A, bfA, true, true, true, false);
        SLICE_BODY(6 * t + 4, 1, 2, af0A, bfA, af0B, bfB, true, true, true, false);
        SLICE_BODY(6 * t + 5, 2, 0, af0B, bfB, af0A, bfA, true, true, true, false);
    }
    // --- tail: slices 60..63. Stages off past 61; vmcnt(0) at 62 (A63,B63
    // must land before h1(62) reads them); no prefetch at 63.
    SLICE_BODY(60, 0, 1, af0A, bfA, af0B, bfB, true,  true,  true,  false);
    SLICE_BODY(61, 1, 2, af0B, bfB, af0A, bfA, true,  true,  true,  false);
    SLICE_BODY(62, 2, 0, af0A, bfA, af0B, bfB, false, false, true,  true);
    SLICE_BODY(63, 0, 1, af0B, bfB, af0A, bfA, false, false, false, false);

#undef SLICE_BODY
#undef STAGE_A
#undef STAGE_B

    // --- epilogue: C/D layout col = lane&15, row = quad*4 + reg
    float bv[4];
    #pragma unroll
    for (int n = 0; n < 4; ++n)
        bv[n] = bias[nBase + wn * 64 + n * 16 + l16];

    #pragma unroll
    for (int m = 0; m < 8; ++m) {
        #pragma unroll
        for (int n = 0; n < 4; ++n) {
            const int col = nBase + wn * 64 + n * 16 + l16;
            #pragma unroll
            for (int r = 0; r < 4; ++r) {
                const int row = mBase + wm * 128 + m * 16 + quad * 4 + r;
                C[(size_t)row * N + col] = acc[m][n][r] + bv[n];
            }
        }
    }
}

extern "C" void kernel_launch(void* const* d_in, const int* in_sizes, int n_in,
                              void* d_out, int out_size, void* d_ws, size_t ws_size,
                              hipStream_t stream) {
    const float* x      = (const float*)d_in[0];  // [B][Cin][8]
    const float* weight = (const float*)d_in[1];  // [Cout][Cin][8]
    const float* bias   = (const float*)d_in[2];  // [Cout][8]
    const float* cayley = (const float*)d_in[3];  // [8][8][8]
    float* out = (float*)d_out;                   // [B][Cout][8]

    const int Cout = in_sizes[2] / 8;
    const int Cin  = in_sizes[1] / (Cout * 8);
    const int Bm   = in_sizes[0] / (Cin * 8);
    const int M = Bm;          // 8192
    const int N = Cout * 8;    // 2048
    const int K = Cin * 8;     // 2048

    __bf16* Xb = (__bf16*)d_ws;                               // M*K bf16 = 32 MB
    __bf16* Wt = (__bf16*)((char*)d_ws + (size_t)M * K * 2);  // N*K bf16 = 8 MB

    long nx = (long)M * K;
    int castBlocks = (int)(nx / 8 / 256);               // nx divisible by 2048
    int foldBlocks = (N * Cin + 255) / 256;
    prep_kernel<<<castBlocks + foldBlocks, 256, 0, stream>>>(
        x, Xb, nx, weight, cayley, Wt, Cin, Cout, castBlocks);

    // GEMM: 256x128 tiles, 32 x 16 = 512 blocks, 256 threads (4 waves),
    // 72 KB LDS -> 2 blocks/CU for cross-block pipe overlap.
    int grid = (M / BM) * (N / BN);
    gemm_bt_kernel<<<grid, 256, 0, stream>>>(Xb, Wt, bias, out, M, N, K);
}